// Round 1
// baseline (4070.755 us; speedup 1.0000x reference)
//
#include <hip/hip_runtime.h>
#include <math.h>

#define N_NODES_C 100000
#define N_EDGES_C 3200000
// D_NODE=16, D_EDGE=8, D_HIDDEN=16

#define NORM_MSG_TP 0.08838834764831845f   // 1/sqrt(16*8)
#define NORM_UPD_TP 0.0625f                // 1/sqrt(16*16)
#define NORM_LIN    0.25f                  // 1/sqrt(16)

__device__ __forceinline__ float silu_f(float v) {
  return v / (1.0f + __expf(-v));
}

__global__ void zero_f4(float4* __restrict__ p, int n4) {
  int i = blockIdx.x * blockDim.x + threadIdx.x;
  if (i < n4) p[i] = make_float4(0.f, 0.f, 0.f, 0.f);
}

#define EPT 2
__global__ __launch_bounds__(256) void edge_kernel(
    const float* __restrict__ x,      // [N,16]
    const float* __restrict__ ea,     // [E,8]
    const float* __restrict__ Wtp,    // [16,8,16]
    const float* __restrict__ Wlin,   // [16,16]
    const int*   __restrict__ eidx,   // [2,E] row=dest, col=src
    float*       __restrict__ agg)    // [N,16]
{
  __shared__ float sW[2048];
  __shared__ float sL[256];
  for (int t = threadIdx.x; t < 2048; t += 256) sW[t] = Wtp[t];
  sL[threadIdx.x] = Wlin[threadIdx.x];
  __syncthreads();

  const long e0 = ((long)blockIdx.x * 256 + threadIdx.x) * EPT;  // grid sized exactly

  float xr[EPT][16], er[EPT][8];
  int rw[EPT];
#pragma unroll
  for (int e = 0; e < EPT; ++e) {
    const long ei = e0 + e;
    const int c = eidx[N_EDGES_C + ei];  // col = source
    rw[e] = eidx[ei];                    // row = dest
    const float4* xp = reinterpret_cast<const float4*>(x + (size_t)c * 16);
#pragma unroll
    for (int q = 0; q < 4; ++q) {
      float4 v = xp[q];
      xr[e][q*4+0] = v.x; xr[e][q*4+1] = v.y; xr[e][q*4+2] = v.z; xr[e][q*4+3] = v.w;
    }
    const float4* ep = reinterpret_cast<const float4*>(ea + (size_t)ei * 8);
#pragma unroll
    for (int q = 0; q < 2; ++q) {
      float4 v = ep[q];
      er[e][q*4+0] = v.x; er[e][q*4+1] = v.y; er[e][q*4+2] = v.z; er[e][q*4+3] = v.w;
    }
  }

  float m[EPT][16];
#pragma unroll
  for (int e = 0; e < EPT; ++e)
#pragma unroll
    for (int h = 0; h < 16; ++h) m[e][h] = 0.f;

  // m[e][h] = sum_{i,j} x[e][i]*ea[e][j]*W[i][j][h]
#pragma unroll
  for (int i = 0; i < 16; ++i) {
#pragma unroll
    for (int j = 0; j < 8; ++j) {
      float p[EPT];
#pragma unroll
      for (int e = 0; e < EPT; ++e) p[e] = xr[e][i] * er[e][j];
      const float* w = &sW[(i*8 + j) * 16];
#pragma unroll
      for (int h = 0; h < 16; ++h) {
        const float wv = w[h];
#pragma unroll
        for (int e = 0; e < EPT; ++e) m[e][h] = fmaf(p[e], wv, m[e][h]);
      }
    }
  }

#pragma unroll
  for (int e = 0; e < EPT; ++e) {
    float g[16];
#pragma unroll
    for (int h = 0; h < 16; ++h) g[h] = silu_f(m[e][h] * NORM_MSG_TP);
    float* ap = agg + (size_t)rw[e] * 16;
#pragma unroll
    for (int h2 = 0; h2 < 16; ++h2) {
      float a = 0.f;
#pragma unroll
      for (int h = 0; h < 16; ++h) a = fmaf(g[h], sL[h*16 + h2], a);
      atomicAdd(ap + h2, a * NORM_LIN);
    }
  }
}

#define NPT 2
__global__ __launch_bounds__(256) void node_kernel(
    const float* __restrict__ x,      // [N,16]
    const float* __restrict__ agg,    // [N,16]
    const float* __restrict__ Wtp,    // [16,16,16]
    const float* __restrict__ Wlin,   // [16,16]
    float*       __restrict__ out)    // [N,16]
{
  __shared__ float sW[4096];
  __shared__ float sL[256];
  for (int t = threadIdx.x; t < 4096; t += 256) sW[t] = Wtp[t];
  sL[threadIdx.x] = Wlin[threadIdx.x];
  __syncthreads();

  const long n0 = ((long)blockIdx.x * 256 + threadIdx.x) * NPT;

  float xr[NPT][16], ar[NPT][16];
  bool valid[NPT];
#pragma unroll
  for (int e = 0; e < NPT; ++e) {
    const long n = n0 + e;
    valid[e] = (n < N_NODES_C);
    if (valid[e]) {
      const float4* xp = reinterpret_cast<const float4*>(x + (size_t)n * 16);
      const float4* ap = reinterpret_cast<const float4*>(agg + (size_t)n * 16);
#pragma unroll
      for (int q = 0; q < 4; ++q) {
        float4 v = xp[q];
        xr[e][q*4+0] = v.x; xr[e][q*4+1] = v.y; xr[e][q*4+2] = v.z; xr[e][q*4+3] = v.w;
        float4 w = ap[q];
        ar[e][q*4+0] = w.x; ar[e][q*4+1] = w.y; ar[e][q*4+2] = w.z; ar[e][q*4+3] = w.w;
      }
    } else {
#pragma unroll
      for (int q = 0; q < 16; ++q) { xr[e][q] = 0.f; ar[e][q] = 0.f; }
    }
  }

  float u[NPT][16];
#pragma unroll
  for (int e = 0; e < NPT; ++e)
#pragma unroll
    for (int k = 0; k < 16; ++k) u[e][k] = 0.f;

  // u[e][k] = sum_{i,h} x[e][i]*agg[e][h]*W[i][h][k]
#pragma unroll
  for (int i = 0; i < 16; ++i) {
#pragma unroll
    for (int h = 0; h < 16; ++h) {
      float p[NPT];
#pragma unroll
      for (int e = 0; e < NPT; ++e) p[e] = xr[e][i] * ar[e][h];
      const float* w = &sW[(i*16 + h) * 16];
#pragma unroll
      for (int k = 0; k < 16; ++k) {
        const float wv = w[k];
#pragma unroll
        for (int e = 0; e < NPT; ++e) u[e][k] = fmaf(p[e], wv, u[e][k]);
      }
    }
  }

#pragma unroll
  for (int e = 0; e < NPT; ++e) {
    if (!valid[e]) continue;
    const long n = n0 + e;
    float g[16];
#pragma unroll
    for (int k = 0; k < 16; ++k) g[k] = silu_f(u[e][k] * NORM_UPD_TP);
    float res[16];
#pragma unroll
    for (int k2 = 0; k2 < 16; ++k2) {
      float a = 0.f;
#pragma unroll
      for (int k = 0; k < 16; ++k) a = fmaf(g[k], sL[k*16 + k2], a);
      res[k2] = xr[e][k2] + a * NORM_LIN;
    }
    float4* op = reinterpret_cast<float4*>(out + (size_t)n * 16);
#pragma unroll
    for (int q = 0; q < 4; ++q)
      op[q] = make_float4(res[q*4+0], res[q*4+1], res[q*4+2], res[q*4+3]);
  }
}

extern "C" void kernel_launch(void* const* d_in, const int* in_sizes, int n_in,
                              void* d_out, int out_size, void* d_ws, size_t ws_size,
                              hipStream_t stream) {
  const float* node_features = (const float*)d_in[0];
  const float* edge_attr     = (const float*)d_in[1];
  // d_in[2] node_attr_scalar_raw: unused by the reference
  const float* W_msg_tp      = (const float*)d_in[3];
  const float* W_msg_lin     = (const float*)d_in[4];
  const float* W_upd_tp      = (const float*)d_in[5];
  const float* W_upd_lin     = (const float*)d_in[6];
  const int*   edge_index    = (const int*)d_in[7];
  float* out = (float*)d_out;
  float* agg = (float*)d_ws;   // N_NODES*16 floats = 6.4 MB

  // zero the aggregation buffer (must happen every launch)
  const int n4 = N_NODES_C * 16 / 4;
  hipLaunchKernelGGL(zero_f4, dim3((n4 + 255) / 256), dim3(256), 0, stream,
                     (float4*)agg, n4);

  // edge phase: 3.2M edges, EPT per thread, grid divides exactly (3.2M/512=6250)
  hipLaunchKernelGGL(edge_kernel, dim3(N_EDGES_C / (256 * EPT)), dim3(256), 0, stream,
                     node_features, edge_attr, W_msg_tp, W_msg_lin, edge_index, agg);

  // node phase
  const int nblk = (N_NODES_C + 256 * NPT - 1) / (256 * NPT);
  hipLaunchKernelGGL(node_kernel, dim3(nblk), dim3(256), 0, stream,
                     node_features, agg, W_upd_tp, W_upd_lin, out);
}

// Round 3
// 2645.338 us; speedup vs baseline: 1.5388x; 1.5388x over previous
//
#include <hip/hip_runtime.h>
#include <math.h>

#define N_NODES_C 100000
#define N_EDGES_C 3200000
// D_NODE=16, D_EDGE=8, D_HIDDEN=16

#define NORM_MSG_TP 0.08838834764831845f   // 1/sqrt(16*8)
#define NORM_UPD_TP 0.0625f                // 1/sqrt(16*16)
#define NORM_LIN    0.25f                  // 1/sqrt(16)

__device__ __forceinline__ float silu_f(float v) {
  return v / (1.0f + __expf(-v));
}

// HW fp32 atomic add (global_atomic_add_f32, memory-side at L2).
// Plain atomicAdd(float*) compiles to a CAS loop on gfx9xx -- 10x slower.
__device__ __forceinline__ void atomic_add_hw(float* p, float v) {
  unsafeAtomicAdd(p, v);
}

__global__ void zero_f4(float4* __restrict__ p, int n4) {
  int i = blockIdx.x * blockDim.x + threadIdx.x;
  if (i < n4) p[i] = make_float4(0.f, 0.f, 0.f, 0.f);
}

#define EPT 2
__global__ __launch_bounds__(256) void edge_kernel(
    const float* __restrict__ x,      // [N,16]
    const float* __restrict__ ea,     // [E,8]
    const float* __restrict__ Wtp,    // [16,8,16]
    const float* __restrict__ Wlin,   // [16,16]
    const int*   __restrict__ eidx,   // [2,E] row=dest, col=src
    float*       __restrict__ agg)    // [N,16]
{
  __shared__ float sW[2048];
  __shared__ float sL[256];
  for (int t = threadIdx.x; t < 2048; t += 256) sW[t] = Wtp[t];
  sL[threadIdx.x] = Wlin[threadIdx.x];
  __syncthreads();

  const long e0 = ((long)blockIdx.x * 256 + threadIdx.x) * EPT;  // grid sized exactly

  float xr[EPT][16], er[EPT][8];
  int rw[EPT];
#pragma unroll
  for (int e = 0; e < EPT; ++e) {
    const long ei = e0 + e;
    const int c = eidx[N_EDGES_C + ei];  // col = source
    rw[e] = eidx[ei];                    // row = dest
    const float4* xp = reinterpret_cast<const float4*>(x + (size_t)c * 16);
#pragma unroll
    for (int q = 0; q < 4; ++q) {
      float4 v = xp[q];
      xr[e][q*4+0] = v.x; xr[e][q*4+1] = v.y; xr[e][q*4+2] = v.z; xr[e][q*4+3] = v.w;
    }
    const float4* ep = reinterpret_cast<const float4*>(ea + (size_t)ei * 8);
#pragma unroll
    for (int q = 0; q < 2; ++q) {
      float4 v = ep[q];
      er[e][q*4+0] = v.x; er[e][q*4+1] = v.y; er[e][q*4+2] = v.z; er[e][q*4+3] = v.w;
    }
  }

  float m[EPT][16];
#pragma unroll
  for (int e = 0; e < EPT; ++e)
#pragma unroll
    for (int h = 0; h < 16; ++h) m[e][h] = 0.f;

  // m[e][h] = sum_{i,j} x[e][i]*ea[e][j]*W[i][j][h]
#pragma unroll
  for (int i = 0; i < 16; ++i) {
#pragma unroll
    for (int j = 0; j < 8; ++j) {
      float p[EPT];
#pragma unroll
      for (int e = 0; e < EPT; ++e) p[e] = xr[e][i] * er[e][j];
      const float* w = &sW[(i*8 + j) * 16];
#pragma unroll
      for (int h = 0; h < 16; ++h) {
        const float wv = w[h];
#pragma unroll
        for (int e = 0; e < EPT; ++e) m[e][h] = fmaf(p[e], wv, m[e][h]);
      }
    }
  }

#pragma unroll
  for (int e = 0; e < EPT; ++e) {
    float g[16];
#pragma unroll
    for (int h = 0; h < 16; ++h) g[h] = silu_f(m[e][h] * NORM_MSG_TP);
    float* ap = agg + (size_t)rw[e] * 16;
#pragma unroll
    for (int h2 = 0; h2 < 16; ++h2) {
      float a = 0.f;
#pragma unroll
      for (int h = 0; h < 16; ++h) a = fmaf(g[h], sL[h*16 + h2], a);
      atomic_add_hw(ap + h2, a * NORM_LIN);
    }
  }
}

__global__ __launch_bounds__(256) void node_kernel(
    const float* __restrict__ x,      // [N,16]
    const float* __restrict__ agg,    // [N,16]
    const float* __restrict__ Wtp,    // [16,16,16]
    const float* __restrict__ Wlin,   // [16,16]
    float*       __restrict__ out)    // [N,16]
{
  __shared__ float sW[4096];
  __shared__ float sL[256];
  for (int t = threadIdx.x; t < 4096; t += 256) sW[t] = Wtp[t];
  sL[threadIdx.x] = Wlin[threadIdx.x];
  __syncthreads();

  const long n = (long)blockIdx.x * 256 + threadIdx.x;
  if (n >= N_NODES_C) return;

  float xr[16], ar[16];
  const float4* xp = reinterpret_cast<const float4*>(x + (size_t)n * 16);
  const float4* ap = reinterpret_cast<const float4*>(agg + (size_t)n * 16);
#pragma unroll
  for (int q = 0; q < 4; ++q) {
    float4 v = xp[q];
    xr[q*4+0] = v.x; xr[q*4+1] = v.y; xr[q*4+2] = v.z; xr[q*4+3] = v.w;
    float4 w = ap[q];
    ar[q*4+0] = w.x; ar[q*4+1] = w.y; ar[q*4+2] = w.z; ar[q*4+3] = w.w;
  }

  float u[16];
#pragma unroll
  for (int k = 0; k < 16; ++k) u[k] = 0.f;

  // u[k] = sum_{i,h} x[i]*agg[h]*W[i][h][k]
#pragma unroll
  for (int i = 0; i < 16; ++i) {
#pragma unroll
    for (int h = 0; h < 16; ++h) {
      const float p = xr[i] * ar[h];
      const float* w = &sW[(i*16 + h) * 16];
#pragma unroll
      for (int k = 0; k < 16; ++k) u[k] = fmaf(p, w[k], u[k]);
    }
  }

  float g[16];
#pragma unroll
  for (int k = 0; k < 16; ++k) g[k] = silu_f(u[k] * NORM_UPD_TP);
  float res[16];
#pragma unroll
  for (int k2 = 0; k2 < 16; ++k2) {
    float a = 0.f;
#pragma unroll
    for (int k = 0; k < 16; ++k) a = fmaf(g[k], sL[k*16 + k2], a);
    res[k2] = xr[k2] + a * NORM_LIN;
  }
  float4* op = reinterpret_cast<float4*>(out + (size_t)n * 16);
#pragma unroll
  for (int q = 0; q < 4; ++q)
    op[q] = make_float4(res[q*4+0], res[q*4+1], res[q*4+2], res[q*4+3]);
}

extern "C" void kernel_launch(void* const* d_in, const int* in_sizes, int n_in,
                              void* d_out, int out_size, void* d_ws, size_t ws_size,
                              hipStream_t stream) {
  const float* node_features = (const float*)d_in[0];
  const float* edge_attr     = (const float*)d_in[1];
  // d_in[2] node_attr_scalar_raw: unused by the reference
  const float* W_msg_tp      = (const float*)d_in[3];
  const float* W_msg_lin     = (const float*)d_in[4];
  const float* W_upd_tp      = (const float*)d_in[5];
  const float* W_upd_lin     = (const float*)d_in[6];
  const int*   edge_index    = (const int*)d_in[7];
  float* out = (float*)d_out;
  float* agg = (float*)d_ws;   // N_NODES*16 floats = 6.4 MB

  // zero the aggregation buffer (must happen every launch)
  const int n4 = N_NODES_C * 16 / 4;
  hipLaunchKernelGGL(zero_f4, dim3((n4 + 255) / 256), dim3(256), 0, stream,
                     (float4*)agg, n4);

  // edge phase: 3.2M edges, EPT per thread, grid divides exactly (3.2M/512=6250)
  hipLaunchKernelGGL(edge_kernel, dim3(N_EDGES_C / (256 * EPT)), dim3(256), 0, stream,
                     node_features, edge_attr, W_msg_tp, W_msg_lin, edge_index, agg);

  // node phase: 1 node/thread
  const int nblk = (N_NODES_C + 255) / 256;
  hipLaunchKernelGGL(node_kernel, dim3(nblk), dim3(256), 0, stream,
                     node_features, agg, W_upd_tp, W_upd_lin, out);
}